// Round 1
// baseline (898.356 us; speedup 1.0000x reference)
//
#include <hip/hip_runtime.h>
#include <hip/hip_bf16.h>
#include <stdint.h>

#define NB 4
#define NH 8
#define SDIM 2048
#define DDIM 64

typedef short s8v __attribute__((ext_vector_type(8)));   // 8 x bf16 (bit pattern)
typedef float f4v __attribute__((ext_vector_type(4)));   // MFMA C/D

__device__ __forceinline__ float bf2f(unsigned short h) {
    union { unsigned int u; float f; } c; c.u = ((unsigned int)h) << 16; return c.f;
}
__device__ __forceinline__ unsigned short f2bf(float x) {
    union { float f; unsigned int u; } c; c.f = x;
    return (unsigned short)((c.u + 0x7FFFu + ((c.u >> 16) & 1u)) >> 16);  // RNE
}

// ---------- prep 1: kb = bf16(k * 0.125)  (scale folded: /8 is exact in bf16) ----------
__global__ void sdpa_prep_cast_k(const float* __restrict__ k, unsigned short* __restrict__ kb) {
    int i = blockIdx.x * 256 + threadIdx.x;           // grid covers exactly n/4 float4s
    float4 v = ((const float4*)k)[i];
    ushort4 o;
    o.x = f2bf(v.x * 0.125f);
    o.y = f2bf(v.y * 0.125f);
    o.z = f2bf(v.z * 0.125f);
    o.w = f2bf(v.w * 0.125f);
    ((ushort4*)kb)[i] = o;
}

// ---------- prep 2: vtb[bh][d][s] = bf16(v[bh][s][d])  (64x64 LDS tile transpose) ----------
__global__ void sdpa_prep_transpose_v(const float* __restrict__ v, unsigned short* __restrict__ vt) {
    __shared__ float t[64][65];
    const int bh = blockIdx.x >> 5;
    const int kt = blockIdx.x & 31;
    const int tid = threadIdx.x;
    const float* src = v + ((size_t)bh * SDIM + (size_t)kt * 64) * DDIM;
    #pragma unroll
    for (int i = 0; i < 4; ++i) {
        int idx = i * 256 + tid;
        int kl = idx >> 4, c4 = idx & 15;
        float4 val = ((const float4*)(src + kl * DDIM))[c4];
        t[kl][c4 * 4 + 0] = val.x; t[kl][c4 * 4 + 1] = val.y;
        t[kl][c4 * 4 + 2] = val.z; t[kl][c4 * 4 + 3] = val.w;
    }
    __syncthreads();
    const int d   = tid >> 2;
    const int klb = (tid & 3) << 4;
    unsigned short* dst = vt + ((size_t)bh * DDIM + d) * SDIM + kt * 64 + klb;
    #pragma unroll
    for (int c = 0; c < 4; ++c) {
        ushort4 w;
        w.x = f2bf(t[klb + c * 4 + 0][d]);
        w.y = f2bf(t[klb + c * 4 + 1][d]);
        w.z = f2bf(t[klb + c * 4 + 2][d]);
        w.w = f2bf(t[klb + c * 4 + 3][d]);
        ((ushort4*)dst)[c] = w;
    }
}

// ---------- main fused kernel: one block = 16 q-rows of one (b,h) ----------
// LDS: sc[16][2048] bf16 = 65536 B exactly (2 blocks/CU). 16B-block XOR swizzle:
//   element (row, col) -> row*2048 + ((col>>3) ^ row)*8 + (col&7)
// keeps all ds_read_b128 / writes at <=2-way bank aliasing (free, m136).
__launch_bounds__(256, 2)
__global__ void sdpa_main(const float* __restrict__ q,
                          const unsigned short* __restrict__ kb,
                          const unsigned short* __restrict__ vtb,
                          const int* __restrict__ mask,
                          float* __restrict__ outO,
                          float* __restrict__ outP) {
    extern __shared__ char lds[];
    unsigned short* sc = (unsigned short*)lds;

    const int bx = blockIdx.x;
    const int bh = bx >> 7;            // 128 q-tiles per (b,h)
    const int q0 = (bx & 127) << 4;
    const int b  = bh >> 3;            // H = 8

    const int tid  = threadIdx.x;
    const int wave = tid >> 6;
    const int lane = tid & 63;
    const int l15  = lane & 15;
    const int quad = lane >> 4;

    // ---- Q A-fragments straight from global fp32: A[m=l15][k=ka*32+quad*8+j] ----
    s8v aq0, aq1;
    {
        const float* qr = q + ((size_t)bh * SDIM + q0 + l15) * DDIM + quad * 8;
        float4 x0 = ((const float4*)qr)[0];
        float4 x1 = ((const float4*)qr)[1];
        float4 y0 = ((const float4*)(qr + 32))[0];
        float4 y1 = ((const float4*)(qr + 32))[1];
        aq0[0]=(short)f2bf(x0.x); aq0[1]=(short)f2bf(x0.y); aq0[2]=(short)f2bf(x0.z); aq0[3]=(short)f2bf(x0.w);
        aq0[4]=(short)f2bf(x1.x); aq0[5]=(short)f2bf(x1.y); aq0[6]=(short)f2bf(x1.z); aq0[7]=(short)f2bf(x1.w);
        aq1[0]=(short)f2bf(y0.x); aq1[1]=(short)f2bf(y0.y); aq1[2]=(short)f2bf(y0.z); aq1[3]=(short)f2bf(y0.w);
        aq1[4]=(short)f2bf(y1.x); aq1[5]=(short)f2bf(y1.y); aq1[6]=(short)f2bf(y1.z); aq1[7]=(short)f2bf(y1.w);
    }

    // ---- phase 1: scores = Q*(K/8)^T, wave w owns kpos [512w, 512w+512) ----
    {
        const unsigned short* kbase = kb + (size_t)bh * SDIM * DDIM;
        const int n_start = wave << 9;
        #pragma unroll 2
        for (int t = 0; t < 32; ++t) {
            const int n0 = n_start + (t << 4);
            const unsigned short* krow = kbase + (size_t)(n0 + l15) * DDIM + quad * 8;
            s8v b0 = *(const s8v*)(krow);
            s8v b1 = *(const s8v*)(krow + 32);
            f4v acc = {0.f, 0.f, 0.f, 0.f};
            acc = __builtin_amdgcn_mfma_f32_16x16x32_bf16(aq0, b0, acc, 0, 0, 0);
            acc = __builtin_amdgcn_mfma_f32_16x16x32_bf16(aq1, b1, acc, 0, 0, 0);
            const int col = n0 + l15;
            const int blk = col >> 3;
            const int off = col & 7;
            #pragma unroll
            for (int r = 0; r < 4; ++r) {
                int row = quad * 4 + r;                       // C row = q-row
                sc[row * 2048 + (((blk ^ row) << 3) | off)] = f2bf(acc[r]);
            }
        }
    }
    __syncthreads();

    // ---- row passes: thread t owns row = t>>4, columns {l16+16i}*8 ----
    const int row = tid >> 4;
    const int l16 = tid & 15;
    unsigned short* scrow = sc + row * 2048;
    const int* mrow = mask + (size_t)b * SDIM * SDIM + (size_t)(q0 + row) * SDIM;

    // pass A: apply mask, find row max (write masked scores back)
    float rmax = -3.0e38f;
    for (int i = 0; i < 16; ++i) {
        int j = l16 + (i << 4);
        unsigned short* p = scrow + (((j ^ row) << 3));
        s8v vv = *(s8v*)p;
        int4 m0 = ((const int4*)mrow)[j * 2 + 0];
        int4 m1 = ((const int4*)mrow)[j * 2 + 1];
        int mm[8] = { m0.x, m0.y, m0.z, m0.w, m1.x, m1.y, m1.z, m1.w };
        #pragma unroll
        for (int e = 0; e < 8; ++e) {
            float s = bf2f((unsigned short)vv[e]);
            s = (mm[e] == 0) ? -1.0e9f : s;
            rmax = fmaxf(rmax, s);
            vv[e] = (short)f2bf(s);
        }
        *(s8v*)p = vv;
    }
    #pragma unroll
    for (int d = 1; d < 16; d <<= 1) rmax = fmaxf(rmax, __shfl_xor(rmax, d));

    // pass B: e = exp(s - max), row sum, store e (bf16) back
    float rsum = 0.f;
    for (int i = 0; i < 16; ++i) {
        int j = l16 + (i << 4);
        unsigned short* p = scrow + (((j ^ row) << 3));
        s8v vv = *(s8v*)p;
        #pragma unroll
        for (int e = 0; e < 8; ++e) {
            float ex = __expf(bf2f((unsigned short)vv[e]) - rmax);
            rsum += ex;
            vv[e] = (short)f2bf(ex);
        }
        *(s8v*)p = vv;
    }
    #pragma unroll
    for (int d = 1; d < 16; d <<= 1) rsum += __shfl_xor(rsum, d);
    const float rinv = 1.0f / rsum;

    // pass C: write attn = e/sum to global (coalesced), write normalized bf16 back for PV
    {
        float* prow = outP + (size_t)bh * SDIM * SDIM + (size_t)(q0 + row) * SDIM;
        for (int i = 0; i < 16; ++i) {
            int j = l16 + (i << 4);
            unsigned short* p = scrow + (((j ^ row) << 3));
            s8v vv = *(s8v*)p;
            float e0 = bf2f((unsigned short)vv[0]) * rinv;
            float e1 = bf2f((unsigned short)vv[1]) * rinv;
            float e2 = bf2f((unsigned short)vv[2]) * rinv;
            float e3 = bf2f((unsigned short)vv[3]) * rinv;
            float e4 = bf2f((unsigned short)vv[4]) * rinv;
            float e5 = bf2f((unsigned short)vv[5]) * rinv;
            float e6 = bf2f((unsigned short)vv[6]) * rinv;
            float e7 = bf2f((unsigned short)vv[7]) * rinv;
            float4 o0 = { e0, e1, e2, e3 };
            float4 o1 = { e4, e5, e6, e7 };
            ((float4*)prow)[j * 2 + 0] = o0;
            ((float4*)prow)[j * 2 + 1] = o1;
            vv[0]=(short)f2bf(e0); vv[1]=(short)f2bf(e1); vv[2]=(short)f2bf(e2); vv[3]=(short)f2bf(e3);
            vv[4]=(short)f2bf(e4); vv[5]=(short)f2bf(e5); vv[6]=(short)f2bf(e6); vv[7]=(short)f2bf(e7);
            *(s8v*)p = vv;
        }
    }
    __syncthreads();

    // ---- phase 4: O = P * V. Wave w owns d-tile [16w,16w+16). A = P from LDS, B from vtb. ----
    {
        const unsigned short* vbase = vtb + ((size_t)bh * DDIM + (wave << 4) + l15) * SDIM + quad * 8;
        unsigned short* arow = sc + l15 * 2048;      // A row m = l15
        f4v acc0 = {0,0,0,0}, acc1 = {0,0,0,0}, acc2 = {0,0,0,0}, acc3 = {0,0,0,0};
        #pragma unroll 4
        for (int ks = 0; ks < 64; ++ks) {
            const int k0 = ks << 5;
            s8v a  = *(const s8v*)(arow + ((((k0 >> 3) + quad) ^ l15) << 3));
            s8v bb = *(const s8v*)(vbase + k0);
            if ((ks & 3) == 0)      acc0 = __builtin_amdgcn_mfma_f32_16x16x32_bf16(a, bb, acc0, 0, 0, 0);
            else if ((ks & 3) == 1) acc1 = __builtin_amdgcn_mfma_f32_16x16x32_bf16(a, bb, acc1, 0, 0, 0);
            else if ((ks & 3) == 2) acc2 = __builtin_amdgcn_mfma_f32_16x16x32_bf16(a, bb, acc2, 0, 0, 0);
            else                    acc3 = __builtin_amdgcn_mfma_f32_16x16x32_bf16(a, bb, acc3, 0, 0, 0);
        }
        f4v acc = acc0 + acc1 + acc2 + acc3;
        float* orow = outO + ((size_t)bh * SDIM + q0) * DDIM + (wave << 4) + l15;
        #pragma unroll
        for (int r = 0; r < 4; ++r)
            orow[(quad * 4 + r) * DDIM] = acc[r];    // C row = q-row quad*4+r, col = d
    }
}

extern "C" void kernel_launch(void* const* d_in, const int* in_sizes, int n_in,
                              void* d_out, int out_size, void* d_ws, size_t ws_size,
                              hipStream_t stream) {
    const float* q  = (const float*)d_in[0];
    const float* k  = (const float*)d_in[1];
    const float* v  = (const float*)d_in[2];
    const int* mask = (const int*)d_in[3];

    const size_t qkv_elems = (size_t)NB * NH * SDIM * DDIM;     // 4,194,304
    float* outO = (float*)d_out;
    float* outP = (float*)d_out + qkv_elems;

    unsigned short* kb  = (unsigned short*)d_ws;                // 8 MB
    unsigned short* vtb = kb + qkv_elems;                       // 8 MB

    sdpa_prep_cast_k<<<(int)(qkv_elems / 1024), 256, 0, stream>>>(k, kb);
    sdpa_prep_transpose_v<<<NB * NH * (SDIM / 64), 256, 0, stream>>>(v, vtb);
    sdpa_main<<<NB * NH * (SDIM / 16), 256, 65536, stream>>>(q, kb, vtb, mask, outO, outP);
}